// Round 1
// 588.765 us; speedup vs baseline: 1.4257x; 1.4257x over previous
//
#include <hip/hip_runtime.h>
#include <stdint.h>

// Shapes (fixed by the problem)
#define NBATCH 256
#define NA 196      // query rows (a)
#define NB 196      // key/output cols (n)
#define DK 256      // qk depth
#define DIM 1024    // value dim
// SMOOTH * log2(e)
#define SM_C 5.770780163555854f

#define NT 13       // n tiles: 13*16 = 208 >= 196
#define AW 13       // a tiles = active waves in phase 1 (13*16 = 208 >= 196)
#define KSTR 40     // Kt row stride (u16): 80 B rows, 20 dw mod 32 -> <=2-way (free)
#define PSTR 232    // P row stride (u16): 464 B rows, 20 dw mod 32 -> <=2-way (free)
#define KROWS 208
#define PROWS 208

typedef short short8 __attribute__((ext_vector_type(8)));
typedef float floatx4 __attribute__((ext_vector_type(4)));
typedef float f4 __attribute__((ext_vector_type(4)));

__device__ __forceinline__ unsigned short f32_bf16(float f) {
    unsigned u = __builtin_bit_cast(unsigned, f);
    u += 0x7fffu + ((u >> 16) & 1u);   // RNE
    return (unsigned short)(u >> 16);
}
__device__ __forceinline__ float bf16_f32(unsigned short h) {
    return __builtin_bit_cast(float, (unsigned)h << 16);
}

// -----------------------------------------------------------------------------
// Fused kernel: one block per batch, 1024 threads (16 waves).
// Phase 1: S^T = (Q K)^T via MFMA (hi/lo bf16 split), online softmax in regs,
//          P^T written to LDS only (no global round-trip).
// Phase 2: out[d][n] = sum_a Va[d][a]*P[a][n] + Vb[d][n] + gamma, streaming
//          Va/Vb/Out with zero barriers (P resident in LDS), 4 passes x 16 rows.
// LDS: P [208][232] bf16 = 96.5 KB; Kt hi/lo (33 KB) aliased into the same
//      buffer (dead before P is written).
// -----------------------------------------------------------------------------
__global__ __launch_bounds__(1024, 4) void xattn_fused(
    const float* __restrict__ Q,        // [B][NA][DK]
    const float* __restrict__ Kg,       // [B][DK][NB]
    const float* __restrict__ Va,       // [B][DIM][NA]
    const float* __restrict__ Vb,       // [B][DIM][NB]
    const float* __restrict__ gamma,    // [1]
    float* __restrict__ Out)            // [B][DIM][NB]
{
    const int b = blockIdx.x;
    const float* Qb  = Q  + (size_t)b * NA * DK;
    const float* Kb  = Kg + (size_t)b * DK * NB;
    const float* VAb = Va + (size_t)b * DIM * NA;
    const float* VBb = Vb + (size_t)b * DIM * NB;
    float*       Ob  = Out + (size_t)b * DIM * NB;

    __shared__ __align__(16) unsigned short LDSB[PROWS * PSTR];  // 96512 B
    unsigned short* KtHi = LDSB;                  // [208][40] u16
    unsigned short* KtLo = LDSB + KROWS * KSTR;   // [208][40] u16
    unsigned short* Pl   = LDSB;                  // [208][232] u16 (aliases Kt)

    const int tid  = threadIdx.x;
    const int wave = tid >> 6;
    const int lane = tid & 63;
    const int q    = lane >> 4;
    const int lm   = lane & 15;

    // Zero both Kt buffers once (pad rows n in [196,208) must be 0; staging
    // only ever writes n < 196, so pads stay 0 across all 8 chunks).
    // 2 * 208 * 40 u16 = 8320 u32.
    for (int it = tid; it < KROWS * KSTR; it += 1024)
        ((unsigned*)LDSB)[it] = 0;

    // ---------------- phase 1: S^T = (QK)^T, softmax, P -> LDS --------------
    floatx4 acc[NT];
#pragma unroll
    for (int nt = 0; nt < NT; ++nt) acc[nt] = (floatx4){0.f, 0.f, 0.f, 0.f};

    const int aw = wave * 16 + lm;              // this wave-lane's a column
    const int aq = aw < NA ? aw : NA - 1;       // clamp pad rows (never written)
    const float* qrow = Qb + (size_t)aq * DK;

    for (int kc = 0; kc < 8; ++kc) {            // 8 chunks of 32 over DK=256
        const int k0 = kc * 32;
        // Q loads issued before the barrier: latency hides under staging.
        f4 qv0, qv1;
        if (wave < AW) {
            qv0 = *(const f4*)(qrow + k0 + q * 8);
            qv1 = *(const f4*)(qrow + k0 + q * 8 + 4);
        }
        __syncthreads();                        // prev chunk's Kt reads done
        // ---- stage K[k0+kk][n] -> KtHi/KtLo[n][kk] (f32 -> hi/lo bf16) ----
        for (int it = tid; it < 32 * 49; it += 1024) {   // 49 float4 per k-row
            const int kk = it / 49;
            const int n4 = (it % 49) * 4;
            const f4 v = *(const f4*)(Kb + (size_t)(k0 + kk) * NB + n4);
#pragma unroll
            for (int j = 0; j < 4; ++j) {
                const float f = v[j];
                const unsigned short hi = f32_bf16(f);
                KtHi[(n4 + j) * KSTR + kk] = hi;
                KtLo[(n4 + j) * KSTR + kk] = f32_bf16(f - bf16_f32(hi));
            }
        }
        __syncthreads();
        if (wave < AW) {
            short8 qHi, qLo;
#pragma unroll
            for (int j = 0; j < 8; ++j) {
                const float f = (j < 4) ? qv0[j] : qv1[j - 4];
                const unsigned short hi = f32_bf16(f);
                qHi[j] = (short)hi;
                qLo[j] = (short)f32_bf16(f - bf16_f32(hi));
            }
            // D[n][a] += Kt[n][k] * Q^T[k][a]; 3 products for fp32-level acc
#pragma unroll
            for (int nt = 0; nt < NT; ++nt) {
                const short8 kHi = *(const short8*)&KtHi[(nt * 16 + lm) * KSTR + q * 8];
                const short8 kLo = *(const short8*)&KtLo[(nt * 16 + lm) * KSTR + q * 8];
                acc[nt] = __builtin_amdgcn_mfma_f32_16x16x32_bf16(kHi, qHi, acc[nt], 0, 0, 0);
                acc[nt] = __builtin_amdgcn_mfma_f32_16x16x32_bf16(kLo, qHi, acc[nt], 0, 0, 0);
                acc[nt] = __builtin_amdgcn_mfma_f32_16x16x32_bf16(kHi, qLo, acc[nt], 0, 0, 0);
            }
        }
    }

    // ---- softmax over n (per lane column a), registers only ----
    float inv = 0.f;
    if (wave < AW) {
        float m = -3.0e38f;
#pragma unroll
        for (int nt = 0; nt < NT; ++nt)
#pragma unroll
            for (int r = 0; r < 4; ++r) {
                const int n = nt * 16 + q * 4 + r;
                if (n < NB) m = fmaxf(m, acc[nt][r]);
            }
        m = fmaxf(m, __shfl_xor(m, 16));
        m = fmaxf(m, __shfl_xor(m, 32));
        float s = 0.f;
#pragma unroll
        for (int nt = 0; nt < NT; ++nt)
#pragma unroll
            for (int r = 0; r < 4; ++r) {
                const int n = nt * 16 + q * 4 + r;
                const float p = (n < NB) ? exp2f((acc[nt][r] - m) * SM_C) : 0.f;
                acc[nt][r] = p;
                s += p;
            }
        s += __shfl_xor(s, 16);
        s += __shfl_xor(s, 32);
        inv = 1.f / s;
    }

    __syncthreads();   // all Kt reads done -> safe to overwrite aliased region
    // Zero entire P buffer (pads a in [196,224) and rows n in [196,208) must
    // be 0; interior gets overwritten below). 48256 u16 = 24128 u32.
    for (int it = tid; it < (PROWS * PSTR) / 2; it += 1024)
        ((unsigned*)LDSB)[it] = 0;
    __syncthreads();
    if (wave < AW && aw < NA) {
#pragma unroll
        for (int nt = 0; nt < NT; ++nt)
#pragma unroll
            for (int r = 0; r < 4; ++r) {
                const int n = nt * 16 + q * 4 + r;
                if (n < NB)
                    Pl[(size_t)n * PSTR + aw] = f32_bf16(acc[nt][r] * inv);
            }
    }
    __syncthreads();

    // ---------------- phase 2: Out = Va * P + Vb + gamma --------------------
    // All 16 waves, 4 passes x 16 d-rows/wave, no barriers (P lives in LDS).
    const float g = gamma[0];
#pragma unroll 1
    for (int pass = 0; pass < 4; ++pass) {
        const int dbase = pass * 256 + wave * 16;
        const float* varow = VAb + (size_t)(dbase + lm) * NA;
        floatx4 o[NT];
#pragma unroll
        for (int nt = 0; nt < NT; ++nt) o[nt] = (floatx4){0.f, 0.f, 0.f, 0.f};

        for (int ac = 0; ac < 7; ++ac) {        // 7 chunks of 32 over a (196)
            const int a0 = ac * 32 + q * 8;
            short8 aF;
            if (ac < 6) {
                const f4 v0 = *(const f4*)(varow + a0);
                const f4 v1 = *(const f4*)(varow + a0 + 4);
#pragma unroll
                for (int j = 0; j < 8; ++j)
                    aF[j] = (short)f32_bf16((j < 4) ? v0[j] : v1[j - 4]);
            } else {
                // last chunk: per-element clamp (P pad entries are zero)
#pragma unroll
                for (int j = 0; j < 8; ++j) {
                    int a = a0 + j;
                    a = a < NA ? a : NA - 1;
                    aF[j] = (short)f32_bf16(varow[a]);
                }
            }
            // D[d][n] += Va[d][a] * P[a][n]; B-frag = Pl[n][a..a+8]
#pragma unroll
            for (int nt = 0; nt < NT; ++nt) {
                const short8 bF = *(const short8*)&Pl[(size_t)(nt * 16 + lm) * PSTR + ac * 32 + q * 8];
                o[nt] = __builtin_amdgcn_mfma_f32_16x16x32_bf16(aF, bF, o[nt], 0, 0, 0);
            }
        }

        // epilogue: + Vb + gamma, masked n < 196
#pragma unroll
        for (int nt = 0; nt < NT; ++nt) {
            const int n = nt * 16 + lm;
            if (n < NB) {
#pragma unroll
                for (int r = 0; r < 4; ++r) {
                    const size_t off = (size_t)(dbase + q * 4 + r) * NB + n;
                    Ob[off] = o[nt][r] + VBb[off] + g;
                }
            }
        }
    }
}

extern "C" void kernel_launch(void* const* d_in, const int* in_sizes, int n_in,
                              void* d_out, int out_size, void* d_ws, size_t ws_size,
                              hipStream_t stream) {
    const float* Q  = (const float*)d_in[0];   // query_a [256][196][256]
    const float* VA = (const float*)d_in[1];   // value_a [256][1024][196]
    const float* KB = (const float*)d_in[2];   // key_b   [256][256][196]
    const float* VB = (const float*)d_in[3];   // value_b [256][1024][196]
    const float* GM = (const float*)d_in[4];   // gamma   [1]
    float* out = (float*)d_out;
    // Workspace no longer needed: P never leaves LDS.
    xattn_fused<<<NBATCH, 1024, 0, stream>>>(Q, KB, VA, VB, GM, out);
}

// Round 2
// 586.613 us; speedup vs baseline: 1.4309x; 1.0037x over previous
//
#include <hip/hip_runtime.h>
#include <stdint.h>

// Shapes (fixed by the problem)
#define NBATCH 256
#define NA 196      // query rows (a)
#define NB 196      // key/output cols (n)
#define DK 256      // qk depth
#define DIM 1024    // value dim
// SMOOTH * log2(e)
#define SM_C 5.770780163555854f

#define NT 13       // n tiles: 13*16 = 208 >= 196
#define AW 13       // a tiles = active waves in phase 1
#define KSTR 42     // Kt row stride u16: 21 dwords (odd) -> 2-way-free b32 frag reads,
                    // 8-bank staging writes (was 2-bank at stride 40)
#define KROWS 208
#define KBUF (KROWS * KSTR)   // 8736 u16 per Kt buffer
#define PSTR 232    // P row stride u16 (b128 reads slot-balanced, measured OK)
#define PROWS 208

typedef short short8 __attribute__((ext_vector_type(8)));
typedef float floatx4 __attribute__((ext_vector_type(4)));
typedef float f4 __attribute__((ext_vector_type(4)));
typedef unsigned uint4v __attribute__((ext_vector_type(4)));

__device__ __forceinline__ unsigned short f32_bf16(float f) {
    unsigned u = __builtin_bit_cast(unsigned, f);
    u += 0x7fffu + ((u >> 16) & 1u);   // RNE
    return (unsigned short)(u >> 16);
}
__device__ __forceinline__ float bf16_f32(unsigned short h) {
    return __builtin_bit_cast(float, (unsigned)h << 16);
}

// 8 consecutive u16 via 4 x b32 (rows have odd dword stride -> banks spread;
// NOT b128 because rows are only 4B-aligned, which is the point).
__device__ __forceinline__ short8 frag16(const unsigned short* p) {
    uint4v u;
    u[0] = *(const unsigned*)(p + 0);
    u[1] = *(const unsigned*)(p + 2);
    u[2] = *(const unsigned*)(p + 4);
    u[3] = *(const unsigned*)(p + 6);
    return __builtin_bit_cast(short8, u);
}

// -----------------------------------------------------------------------------
// Fused kernel: one block per batch, 1024 threads (16 waves).
// Phase 1: S^T = (QK)^T via MFMA (hi/lo bf16 split), double-buffered K staging
//          with load-early/write-late split (1 barrier per chunk), softmax in
//          regs, P^T -> LDS only.
// Phase 2: out = Va*P + Vb + gamma; Va prefetched 1 chunk ahead, no barriers.
// LDS: P [208][232] bf16 = 96.5 KB; 4 Kt buffers (2 x hi/lo dbuf, 68 KB)
//      aliased into the same region (dead before P is written).
// -----------------------------------------------------------------------------
__global__ __launch_bounds__(1024, 4) void xattn_fused(
    const float* __restrict__ Q,        // [B][NA][DK]
    const float* __restrict__ Kg,       // [B][DK][NB]
    const float* __restrict__ Va,       // [B][DIM][NA]
    const float* __restrict__ Vb,       // [B][DIM][NB]
    const float* __restrict__ gamma,    // [1]
    float* __restrict__ Out)            // [B][DIM][NB]
{
    const int b = blockIdx.x;
    const float* Qb  = Q  + (size_t)b * NA * DK;
    const float* Kb  = Kg + (size_t)b * DK * NB;
    const float* VAb = Va + (size_t)b * DIM * NA;
    const float* VBb = Vb + (size_t)b * DIM * NB;
    float*       Ob  = Out + (size_t)b * DIM * NB;

    __shared__ __align__(16) unsigned short LDSB[PROWS * PSTR];  // 96512 B
    unsigned short* Pl = LDSB;                                   // [208][232]

    const int tid  = threadIdx.x;
    const int wave = tid >> 6;
    const int lane = tid & 63;
    const int q    = lane >> 4;
    const int lm   = lane & 15;

    // Zero all 4 Kt buffers once (pad rows n in [196,208) must stay 0; staging
    // only writes n < 196). 4*KBUF u16 = 2*KBUF u32.
    for (int it = tid; it < 2 * KBUF; it += 1024)
        ((unsigned*)LDSB)[it] = 0;

    // ---------------- phase 1: S^T = (QK)^T, softmax, P -> LDS --------------
    floatx4 acc[NT];
#pragma unroll
    for (int nt = 0; nt < NT; ++nt) acc[nt] = (floatx4){0.f, 0.f, 0.f, 0.f};

    const int aw = wave * 16 + lm;              // this wave-lane's a column
    const int aq = aw < NA ? aw : NA - 1;       // clamp pad rows (never written)
    const float* qrow = Qb + (size_t)aq * DK;

    // Staging task decode: it in [0,1568): kk = it/49, n4 = (it%49)*4.
    // Each thread owns it=tid and (if tid<544) it=tid+1024.
    auto sload = [&](int k0, f4* sv) {
        {
            const int kk = tid / 49, n4 = (tid % 49) * 4;
            sv[0] = *(const f4*)(Kb + (size_t)(k0 + kk) * NB + n4);
        }
        if (tid < 544) {
            const int it = tid + 1024;
            const int kk = it / 49, n4 = (it % 49) * 4;
            sv[1] = *(const f4*)(Kb + (size_t)(k0 + kk) * NB + n4);
        }
    };
    auto swrite = [&](unsigned short* Hi, unsigned short* Lo, const f4* sv) {
        {
            const int kk = tid / 49, n4 = (tid % 49) * 4;
#pragma unroll
            for (int j = 0; j < 4; ++j) {
                const float f = sv[0][j];
                const unsigned short hi = f32_bf16(f);
                Hi[(n4 + j) * KSTR + kk] = hi;
                Lo[(n4 + j) * KSTR + kk] = f32_bf16(f - bf16_f32(hi));
            }
        }
        if (tid < 544) {
            const int it = tid + 1024;
            const int kk = it / 49, n4 = (it % 49) * 4;
#pragma unroll
            for (int j = 0; j < 4; ++j) {
                const float f = sv[1][j];
                const unsigned short hi = f32_bf16(f);
                Hi[(n4 + j) * KSTR + kk] = hi;
                Lo[(n4 + j) * KSTR + kk] = f32_bf16(f - bf16_f32(hi));
            }
        }
    };

    // Prologue: stage chunk 0 into buf0, prefetch Q chunk 0.
    {
        f4 sv[2];
        sload(0, sv);
        swrite(LDSB, LDSB + KBUF, sv);
    }
    f4 qv0, qv1;
    if (wave < AW) {
        qv0 = *(const f4*)(qrow + q * 8);
        qv1 = *(const f4*)(qrow + q * 8 + 4);
    }
    __syncthreads();   // buf0 + zero-pads complete

#pragma unroll 1
    for (int kc = 0; kc < 8; ++kc) {            // 8 chunks of 32 over DK=256
        unsigned short* HiC = (kc & 1) ? (LDSB + 2 * KBUF) : LDSB;
        unsigned short* LoC = HiC + KBUF;
        unsigned short* HiN = (kc & 1) ? LDSB : (LDSB + 2 * KBUF);
        unsigned short* LoN = HiN + KBUF;

        f4 sv[2];
        if (kc < 7) sload((kc + 1) * 32, sv);   // issue early: hides under MFMA

        f4 qn0, qn1;
        if (wave < AW && kc < 7) {
            qn0 = *(const f4*)(qrow + (kc + 1) * 32 + q * 8);
            qn1 = *(const f4*)(qrow + (kc + 1) * 32 + q * 8 + 4);
        }

        if (wave < AW) {
            short8 qHi, qLo;
#pragma unroll
            for (int j = 0; j < 8; ++j) {
                const float f = (j < 4) ? qv0[j] : qv1[j - 4];
                const unsigned short hi = f32_bf16(f);
                qHi[j] = (short)hi;
                qLo[j] = (short)f32_bf16(f - bf16_f32(hi));
            }
            // D[n][a] += Kt[n][k] * Q^T[k][a]; 3 products for fp32-level acc
#pragma unroll
            for (int nt = 0; nt < NT; ++nt) {
                const int ro = (nt * 16 + lm) * KSTR + q * 8;
                const short8 kHi = frag16(HiC + ro);
                const short8 kLo = frag16(LoC + ro);
                acc[nt] = __builtin_amdgcn_mfma_f32_16x16x32_bf16(kHi, qHi, acc[nt], 0, 0, 0);
                acc[nt] = __builtin_amdgcn_mfma_f32_16x16x32_bf16(kLo, qHi, acc[nt], 0, 0, 0);
                acc[nt] = __builtin_amdgcn_mfma_f32_16x16x32_bf16(kHi, qLo, acc[nt], 0, 0, 0);
            }
        }

        if (kc < 7) {
            swrite(HiN, LoN, sv);               // write-late: after MFMA reads
            if (wave < AW) { qv0 = qn0; qv1 = qn1; }
        }
        __syncthreads();  // next buf complete; all reads of cur buf done
    }

    // ---- softmax over n (per lane column a), registers only ----
    float inv = 0.f;
    if (wave < AW) {
        float m = -3.0e38f;
#pragma unroll
        for (int nt = 0; nt < NT; ++nt)
#pragma unroll
            for (int r = 0; r < 4; ++r) {
                const int n = nt * 16 + q * 4 + r;
                if (n < NB) m = fmaxf(m, acc[nt][r]);
            }
        m = fmaxf(m, __shfl_xor(m, 16));
        m = fmaxf(m, __shfl_xor(m, 32));
        float s = 0.f;
#pragma unroll
        for (int nt = 0; nt < NT; ++nt)
#pragma unroll
            for (int r = 0; r < 4; ++r) {
                const int n = nt * 16 + q * 4 + r;
                const float p = (n < NB) ? exp2f((acc[nt][r] - m) * SM_C) : 0.f;
                acc[nt][r] = p;
                s += p;
            }
        s += __shfl_xor(s, 16);
        s += __shfl_xor(s, 32);
        inv = 1.f / s;
    }

    // Zero entire P buffer (pads must be 0; interior overwritten below).
    // Safe: last loop barrier ordered all Kt reads before this.
    for (int it = tid; it < (PROWS * PSTR) / 2; it += 1024)
        ((unsigned*)LDSB)[it] = 0;
    __syncthreads();
    if (wave < AW && aw < NA) {
#pragma unroll
        for (int nt = 0; nt < NT; ++nt)
#pragma unroll
            for (int r = 0; r < 4; ++r) {
                const int n = nt * 16 + q * 4 + r;
                if (n < NB)
                    Pl[(size_t)n * PSTR + aw] = f32_bf16(acc[nt][r] * inv);
            }
    }
    __syncthreads();

    // ---------------- phase 2: Out = Va * P + Vb + gamma --------------------
    // All 16 waves, 4 passes x 16 d-rows/wave, no barriers; Va 1-chunk prefetch.
    // Clamped f4 loads: base min(a,192) stays in-bounds; clamped lanes multiply
    // zeroed P pads, so values are don't-care.
    const float g = gamma[0];
#pragma unroll 1
    for (int pass = 0; pass < 4; ++pass) {
        const int dbase = pass * 256 + wave * 16;
        const float* varow = VAb + (size_t)(dbase + lm) * NA;
        floatx4 o[NT];
#pragma unroll
        for (int nt = 0; nt < NT; ++nt) o[nt] = (floatx4){0.f, 0.f, 0.f, 0.f};

        f4 c0 = *(const f4*)(varow + q * 8);
        f4 c1 = *(const f4*)(varow + q * 8 + 4);

#pragma unroll
        for (int ac = 0; ac < 7; ++ac) {
            f4 n0, n1;
            if (ac < 6) {
                const int a0 = (ac + 1) * 32 + q * 8;
                n0 = *(const f4*)(varow + (a0     <= 192 ? a0     : 192));
                n1 = *(const f4*)(varow + (a0 + 4 <= 192 ? a0 + 4 : 192));
            }
            short8 aF;
#pragma unroll
            for (int j = 0; j < 8; ++j)
                aF[j] = (short)f32_bf16((j < 4) ? c0[j] : c1[j - 4]);
            // D[d][n] += Va[d][a] * P[a][n]
#pragma unroll
            for (int nt = 0; nt < NT; ++nt) {
                const short8 bF = *(const short8*)&Pl[(size_t)(nt * 16 + lm) * PSTR + ac * 32 + q * 8];
                o[nt] = __builtin_amdgcn_mfma_f32_16x16x32_bf16(aF, bF, o[nt], 0, 0, 0);
            }
            if (ac < 6) { c0 = n0; c1 = n1; }
        }

        // epilogue: + Vb + gamma, masked n < 196, 64 B coalesced runs
#pragma unroll
        for (int nt = 0; nt < NT; ++nt) {
            const int n = nt * 16 + lm;
            if (n < NB) {
#pragma unroll
                for (int r = 0; r < 4; ++r) {
                    const size_t off = (size_t)(dbase + q * 4 + r) * NB + n;
                    Ob[off] = o[nt][r] + VBb[off] + g;
                }
            }
        }
    }
}

extern "C" void kernel_launch(void* const* d_in, const int* in_sizes, int n_in,
                              void* d_out, int out_size, void* d_ws, size_t ws_size,
                              hipStream_t stream) {
    const float* Q  = (const float*)d_in[0];   // query_a [256][196][256]
    const float* VA = (const float*)d_in[1];   // value_a [256][1024][196]
    const float* KB = (const float*)d_in[2];   // key_b   [256][256][196]
    const float* VB = (const float*)d_in[3];   // value_b [256][1024][196]
    const float* GM = (const float*)d_in[4];   // gamma   [1]
    float* out = (float*)d_out;
    // Workspace unused: P never leaves LDS.
    xattn_fused<<<NBATCH, 1024, 0, stream>>>(Q, KB, VA, VB, GM, out);
}